// Round 6
// baseline (478.775 us; speedup 1.0000x reference)
//
#include <hip/hip_runtime.h>
#include <hip/hip_fp16.h>
#include <math.h>

#define NODES 50000
#define EDGES 800000
#define NB_SCAN ((NODES + 1023) / 1024)

typedef __attribute__((ext_vector_type(8))) _Float16 f16x8;
typedef __attribute__((ext_vector_type(4))) _Float16 f16x4;
typedef __attribute__((ext_vector_type(4))) float f32x4;

__device__ __forceinline__ float lrelu02(float x){ return x > 0.f ? x : 0.2f * x; }

// ---------------- CSR build ----------------

__global__ __launch_bounds__(256) void gat_zero(int* __restrict__ p, int n){
  int i = blockIdx.x * 256 + threadIdx.x;
  if (i < n) p[i] = 0;
}

__global__ __launch_bounds__(256) void gat_hist(const int* __restrict__ ei, int* __restrict__ cnt){
  int e = blockIdx.x * 256 + threadIdx.x;
  if (e < EDGES) atomicAdd(&cnt[ei[EDGES + e]], 1);
}

__global__ __launch_bounds__(256) void gat_blocksum(const int* __restrict__ cnt, int* __restrict__ bsums){
  __shared__ int sd[256];
  int t = threadIdx.x, b = blockIdx.x;
  int base = b * 1024 + t * 4, s = 0;
  #pragma unroll
  for (int j = 0; j < 4; j++){ int i = base + j; if (i < NODES) s += cnt[i]; }
  sd[t] = s; __syncthreads();
  for (int o = 128; o > 0; o >>= 1){ if (t < o) sd[t] += sd[t + o]; __syncthreads(); }
  if (t == 0) bsums[b] = sd[0];
}

__global__ void gat_scan_bsums(int* bsums, int nb){
  if (threadIdx.x == 0 && blockIdx.x == 0){
    int run = 0;
    for (int i = 0; i < nb; i++){ int v = bsums[i]; bsums[i] = run; run += v; }
  }
}

__global__ __launch_bounds__(256) void gat_rowptr(int* __restrict__ cnt, const int* __restrict__ bsums,
                                                  int* __restrict__ row_ptr){
  __shared__ int sd[256];
  int t = threadIdx.x, b = blockIdx.x;
  int base = b * 1024 + t * 4;
  int c[4]; int s = 0;
  #pragma unroll
  for (int j = 0; j < 4; j++){
    int i = base + j;
    c[j] = (i < NODES) ? cnt[i] : 0;
    s += c[j];
    if (i < NODES) cnt[i] = 0;
  }
  sd[t] = s; __syncthreads();
  for (int o = 1; o < 256; o <<= 1){
    int v = (t >= o) ? sd[t - o] : 0;
    __syncthreads();
    if (t >= o) sd[t] += v;
    __syncthreads();
  }
  int off = bsums[b] + sd[t] - s;
  #pragma unroll
  for (int j = 0; j < 4; j++){
    int i = base + j;
    if (i < NODES){ row_ptr[i] = off; off += c[j]; }
  }
  if (b == 0 && t == 0) row_ptr[NODES] = EDGES;
}

__global__ __launch_bounds__(256) void gat_scatter(const int* __restrict__ ei, const int* __restrict__ row_ptr,
                                                    int* __restrict__ fill, int* __restrict__ col,
                                                    int* __restrict__ dstarr){
  int e = blockIdx.x * 256 + threadIdx.x;
  if (e < EDGES){
    int s = ei[e], d = ei[EDGES + e];
    int pos = row_ptr[d] + atomicAdd(&fill[d], 1);
    col[pos] = s;
    dstarr[pos] = d;
  }
}

// ---------------- fp32 -> fp16 convert / W transpose ----------------

__global__ __launch_bounds__(256) void gat_cvt_h(const float* __restrict__ src, _Float16* __restrict__ dst, int n4){
  int i = blockIdx.x * 256 + threadIdx.x;
  if (i < n4){
    float4 v = *(const float4*)(src + (size_t)i * 4);
    f16x4 h = { (_Float16)v.x, (_Float16)v.y, (_Float16)v.z, (_Float16)v.w };
    *(f16x4*)(dst + (size_t)i * 4) = h;
  }
}

// Wt[n][k] = (half)W[k][n];  grid = (ceil(N/256), K)
__global__ __launch_bounds__(256) void gat_wt(const float* __restrict__ W, _Float16* __restrict__ Wt, int K, int N){
  int n = blockIdx.x * 256 + threadIdx.x;
  int k = blockIdx.y;
  if (n < N) Wt[(size_t)n * K + k] = (_Float16)W[(size_t)k * N + n];
}

// ws[h*64+c] = sum_cc W0[c][h*64+cc]*a_src0[h][cc]
__global__ __launch_bounds__(256) void gat_ws0(const float* __restrict__ W0, const float* __restrict__ a_src0,
                                               const float* __restrict__ a_dst0,
                                               float* __restrict__ ws, float* __restrict__ wd){
  int t = threadIdx.x;
  int h = t >> 6, c = t & 63;
  float s = 0.f, d = 0.f;
  for (int cc = 0; cc < 64; cc++){
    float w = W0[(size_t)c * 256 + h * 64 + cc];
    s += w * a_src0[h * 64 + cc];
    d += w * a_dst0[h * 64 + cc];
  }
  ws[h * 64 + c] = s;
  wd[h * 64 + c] = d;
}

// ---------------- MFMA fp16 GEMM: C[M,N] = A[M,K] @ W[K,N], Wt = W^T [N][K] ----------------

template<int K, int N>
__global__ __launch_bounds__(256) void gat_gemm_mfma(const _Float16* __restrict__ A, const _Float16* __restrict__ Wt,
                                                      _Float16* __restrict__ C, int M){
  constexpr int NT = N / 64;
  constexpr int LDT = 40;
  __shared__ _Float16 As[64][LDT];
  __shared__ _Float16 Bs[N][LDT];

  int tid = threadIdx.x;
  int w = tid >> 6, l = tid & 63;
  int lg = l >> 4, lr = l & 15;
  int bm = blockIdx.x * 64;

  f32x4 acc[4][NT];
  #pragma unroll
  for (int m = 0; m < 4; m++)
    #pragma unroll
    for (int n = 0; n < NT; n++)
      acc[m][n] = (f32x4){0.f, 0.f, 0.f, 0.f};

  int ar = tid >> 2;
  int akc = (tid & 3) * 8;
  bool avalid = (bm + ar) < M;
  const _Float16* aptr = A + (size_t)(bm + ar) * K + akc;

  for (int k0 = 0; k0 < K; k0 += 32){
    float4 av = avalid ? *(const float4*)(aptr + k0) : make_float4(0.f, 0.f, 0.f, 0.f);
    __syncthreads();
    *(float4*)&As[ar][akc] = av;
    #pragma unroll
    for (int c = 0; c < N / 64; c++){
      int idx = c * 256 + tid;
      int n = idx >> 2, kc = (idx & 3) * 8;
      *(float4*)&Bs[n][kc] = *(const float4*)(Wt + (size_t)n * K + k0 + kc);
    }
    __syncthreads();

    f16x8 af[4], bf[NT];
    #pragma unroll
    for (int m = 0; m < 4; m++) af[m] = *(const f16x8*)&As[16 * m + lr][8 * lg];
    #pragma unroll
    for (int n = 0; n < NT; n++) bf[n] = *(const f16x8*)&Bs[w * (N / 4) + 16 * n + lr][8 * lg];
    #pragma unroll
    for (int m = 0; m < 4; m++)
      #pragma unroll
      for (int n = 0; n < NT; n++)
        acc[m][n] = __builtin_amdgcn_mfma_f32_16x16x32_f16(af[m], bf[n], acc[m][n], 0, 0, 0);
  }

  #pragma unroll
  for (int m = 0; m < 4; m++){
    #pragma unroll
    for (int j = 0; j < 4; j++){
      int row = bm + 16 * m + 4 * lg + j;
      if (row < M){
        #pragma unroll
        for (int n = 0; n < NT; n++)
          C[(size_t)row * N + w * (N / 4) + 16 * n + lr] = (_Float16)acc[m][n][j];
      }
    }
  }
}

// ---------------- block-diagonal per-head GEMM (layer 0 post-aggregate), no LDS ----------------

__global__ __launch_bounds__(256) void gat_gemm_bd(const _Float16* __restrict__ A, const _Float16* __restrict__ Bt,
                                                    const float* __restrict__ bias, _Float16* __restrict__ C, int M){
  int tid = threadIdx.x;
  int w = tid >> 6, l = tid & 63;
  int lg = l >> 4, lr = l & 15;
  int bm = blockIdx.x * 64;

  f32x4 acc[4][4];
  #pragma unroll
  for (int m = 0; m < 4; m++)
    #pragma unroll
    for (int n = 0; n < 4; n++)
      acc[m][n] = (f32x4){0.f, 0.f, 0.f, 0.f};

  f16x8 zf = {};
  #pragma unroll
  for (int ks = 0; ks < 2; ks++){
    int koff = ks * 32;
    f16x8 af[4], bf[4];
    #pragma unroll
    for (int m = 0; m < 4; m++){
      int row = bm + 16 * m + lr;
      af[m] = (row < M) ? *(const f16x8*)(A + (size_t)row * 256 + w * 64 + koff + 8 * lg) : zf;
    }
    #pragma unroll
    for (int n = 0; n < 4; n++)
      bf[n] = *(const f16x8*)(Bt + (size_t)(w * 64 + 16 * n + lr) * 64 + koff + 8 * lg);
    #pragma unroll
    for (int m = 0; m < 4; m++)
      #pragma unroll
      for (int n = 0; n < 4; n++)
        acc[m][n] = __builtin_amdgcn_mfma_f32_16x16x32_f16(af[m], bf[n], acc[m][n], 0, 0, 0);
  }

  #pragma unroll
  for (int m = 0; m < 4; m++){
    #pragma unroll
    for (int j = 0; j < 4; j++){
      int row = bm + 16 * m + 4 * lg + j;
      if (row < M){
        #pragma unroll
        for (int n = 0; n < 4; n++){
          int cc = w * 64 + 16 * n + lr;
          float o = acc[m][n][j] + bias[cc];
          o = o > 0.f ? o : expm1f(o);
          C[(size_t)row * 256 + cc] = (_Float16)o;
        }
      }
    }
  }
}

// ---------------- attention coefficients ----------------

__global__ __launch_bounds__(256) void gat_attn0(const _Float16* __restrict__ xh, const float* __restrict__ ws,
                                                  const float* __restrict__ wd,
                                                  float* __restrict__ asrc, float* __restrict__ adst, int N){
  int lane = threadIdx.x & 63;
  int wid = threadIdx.x >> 6;
  int n = blockIdx.x * 4 + wid;
  if (n >= N) return;
  float v = (float)xh[(size_t)n * 64 + lane];
  #pragma unroll
  for (int h = 0; h < 4; h++){
    float s1 = v * ws[h * 64 + lane];
    float s2 = v * wd[h * 64 + lane];
    #pragma unroll
    for (int o = 32; o > 0; o >>= 1){ s1 += __shfl_xor(s1, o); s2 += __shfl_xor(s2, o); }
    if (lane == 0){ asrc[n * 4 + h] = s1; adst[n * 4 + h] = s2; }
  }
}

// 4-head, 256ch: lane owns 4 channels of one head; 16-lane-group reduction
__global__ __launch_bounds__(256) void gat_attn4(const _Float16* __restrict__ h, const float* __restrict__ a_src,
                                                  const float* __restrict__ a_dst,
                                                  float* __restrict__ asrc, float* __restrict__ adst, int N){
  int lane = threadIdx.x & 63;
  int wid = threadIdx.x >> 6;
  int n = blockIdx.x * 4 + wid;
  if (n >= N) return;
  int co = lane * 4;
  f16x4 hv = *(const f16x4*)(h + (size_t)n * 256 + co);
  float4 av = *(const float4*)&a_src[co];
  float4 dv = *(const float4*)&a_dst[co];
  float f0 = (float)hv[0], f1 = (float)hv[1], f2 = (float)hv[2], f3 = (float)hv[3];
  float s1 = f0 * av.x + f1 * av.y + f2 * av.z + f3 * av.w;
  float s2 = f0 * dv.x + f1 * dv.y + f2 * dv.z + f3 * dv.w;
  #pragma unroll
  for (int o = 8; o > 0; o >>= 1){ s1 += __shfl_xor(s1, o); s2 += __shfl_xor(s2, o); }
  if ((lane & 15) == 0){
    int q = lane >> 4;
    asrc[n * 4 + q] = s1;
    adst[n * 4 + q] = s2;
  }
}

__global__ __launch_bounds__(256) void gat_attn1(const _Float16* __restrict__ h, const float* __restrict__ a_src,
                                                  const float* __restrict__ a_dst,
                                                  float* __restrict__ asrc, float* __restrict__ adst, int N){
  int lane = threadIdx.x & 63;
  int wid = threadIdx.x >> 6;
  int n = blockIdx.x * 4 + wid;
  if (n >= N) return;
  float v = (float)h[(size_t)n * 64 + lane];
  float s1 = v * a_src[lane];
  float s2 = v * a_dst[lane];
  #pragma unroll
  for (int o = 32; o > 0; o >>= 1){ s1 += __shfl_xor(s1, o); s2 += __shfl_xor(s2, o); }
  if (lane == 0){ asrc[n] = s1; adst[n] = s2; }
}

// ---------------- edge exp precompute ----------------

// layer 0: interleaved exf[e][4]
__global__ __launch_bounds__(256) void gat_edge_exp0(const int* __restrict__ col, const int* __restrict__ dstarr,
                                                      const float* __restrict__ asrc, const float* __restrict__ adst,
                                                      float* __restrict__ exf){
  int i = blockIdx.x * 256 + threadIdx.x;
  if (i >= EDGES) return;
  int s = col[i], d = dstarr[i];
  float4 a = *(const float4*)&asrc[s * 4];
  float4 b = *(const float4*)&adst[d * 4];
  float4 r;
  r.x = __expf(lrelu02(a.x + b.x));
  r.y = __expf(lrelu02(a.y + b.y));
  r.z = __expf(lrelu02(a.z + b.z));
  r.w = __expf(lrelu02(a.w + b.w));
  *(float4*)&exf[(size_t)i * 4] = r;
}

// layer 1: head-major exfh[q][e] (so per-head aggregate streams float4s)
__global__ __launch_bounds__(256) void gat_edge_exp4h(const int* __restrict__ col, const int* __restrict__ dstarr,
                                                       const float* __restrict__ asrc, const float* __restrict__ adst,
                                                       float* __restrict__ exfh){
  int i = blockIdx.x * 256 + threadIdx.x;
  if (i >= EDGES) return;
  int s = col[i], d = dstarr[i];
  float4 a = *(const float4*)&asrc[s * 4];
  float4 b = *(const float4*)&adst[d * 4];
  exfh[i]             = __expf(lrelu02(a.x + b.x));
  exfh[EDGES + i]     = __expf(lrelu02(a.y + b.y));
  exfh[2 * EDGES + i] = __expf(lrelu02(a.z + b.z));
  exfh[3 * EDGES + i] = __expf(lrelu02(a.w + b.w));
}

// ---------------- layer-0 aggregate in 64-dim input space (precomputed exps) ----------------

__global__ __launch_bounds__(256) void gat_aggregate_in64(const _Float16* __restrict__ xh, const float* __restrict__ exf,
                                                           const float* __restrict__ asrc, const float* __restrict__ adst,
                                                           const int* __restrict__ row_ptr, const int* __restrict__ col,
                                                           _Float16* __restrict__ agg){
  int lane = threadIdx.x & 63;
  int wid = threadIdx.x >> 6;
  int d = blockIdx.x * 4 + wid;
  if (d >= NODES) return;

  float4 ad4 = *(const float4*)&adst[d * 4];
  float4 a4  = *(const float4*)&asrc[d * 4];
  float ex0 = __expf(lrelu02(a4.x + ad4.x));
  float ex1 = __expf(lrelu02(a4.y + ad4.y));
  float ex2 = __expf(lrelu02(a4.z + ad4.z));
  float ex3 = __expf(lrelu02(a4.w + ad4.w));
  float xv = (float)xh[(size_t)d * 64 + lane];
  float acc0 = ex0 * xv, acc1 = ex1 * xv, acc2 = ex2 * xv, acc3 = ex3 * xv;
  float den0 = ex0, den1 = ex1, den2 = ex2, den3 = ex3;

  int e0 = row_ptr[d], e1 = row_ptr[d + 1];
  const _Float16* xbase = xh + lane;
  int e = e0;
  // peel to 4-alignment for int4 col loads
  for (; e < e1 && (e & 3); e++){
    int s0 = col[e];
    float4 fA = *(const float4*)(exf + (size_t)e * 4);
    float v0 = (float)xbase[(size_t)s0 * 64];
    den0 += fA.x; den1 += fA.y; den2 += fA.z; den3 += fA.w;
    acc0 += fA.x * v0; acc1 += fA.y * v0; acc2 += fA.z * v0; acc3 += fA.w * v0;
  }
  for (; e + 4 <= e1; e += 4){
    int4 c4 = *(const int4*)&col[e];
    float4 fA = *(const float4*)(exf + (size_t)(e)     * 4);
    float4 fB = *(const float4*)(exf + (size_t)(e + 1) * 4);
    float4 fC = *(const float4*)(exf + (size_t)(e + 2) * 4);
    float4 fD = *(const float4*)(exf + (size_t)(e + 3) * 4);
    float v0 = (float)xbase[(size_t)c4.x * 64];
    float v1 = (float)xbase[(size_t)c4.y * 64];
    float v2 = (float)xbase[(size_t)c4.z * 64];
    float v3 = (float)xbase[(size_t)c4.w * 64];
    den0 += fA.x + fB.x + fC.x + fD.x;
    den1 += fA.y + fB.y + fC.y + fD.y;
    den2 += fA.z + fB.z + fC.z + fD.z;
    den3 += fA.w + fB.w + fC.w + fD.w;
    acc0 += fA.x * v0 + fB.x * v1 + fC.x * v2 + fD.x * v3;
    acc1 += fA.y * v0 + fB.y * v1 + fC.y * v2 + fD.y * v3;
    acc2 += fA.z * v0 + fB.z * v1 + fC.z * v2 + fD.z * v3;
    acc3 += fA.w * v0 + fB.w * v1 + fC.w * v2 + fD.w * v3;
  }
  for (; e < e1; e++){
    int s0 = col[e];
    float4 fA = *(const float4*)(exf + (size_t)e * 4);
    float v0 = (float)xbase[(size_t)s0 * 64];
    den0 += fA.x; den1 += fA.y; den2 += fA.z; den3 += fA.w;
    acc0 += fA.x * v0; acc1 += fA.y * v0; acc2 += fA.z * v0; acc3 += fA.w * v0;
  }

  _Float16* ob = agg + (size_t)d * 256 + lane;
  ob[0]   = (_Float16)(acc0 / (den0 + 1e-16f));
  ob[64]  = (_Float16)(acc1 / (den1 + 1e-16f));
  ob[128] = (_Float16)(acc2 / (den2 + 1e-16f));
  ob[192] = (_Float16)(acc3 / (den3 + 1e-16f));
}

// ---------------- layer-1 aggregate: one (dst, head) per wave, XCD-pinned by head ----------------
// grid = 50000 blocks of 256 (4 waves). bid%8 -> XCD (empirical); head = (bid%8)>>1 so each
// XCD touches only ONE head's 6.4 MB line-set of hH (128 B per gather = exactly 1 line).

__global__ __launch_bounds__(256) void gat_aggregate4h(const _Float16* __restrict__ hH,
                                                        const float* __restrict__ exfh,
                                                        const float* __restrict__ asrc, const float* __restrict__ adst,
                                                        const int* __restrict__ row_ptr, const int* __restrict__ col,
                                                        const float* __restrict__ bias, _Float16* __restrict__ out){
  int bid = blockIdx.x;
  int r = bid & 7;
  int q = r >> 1;                       // head, pinned to XCD pair {2q, 2q+1}
  int dq = (bid >> 3) * 2 + (r & 1);    // dst quad in [0, 12500)
  int lane = threadIdx.x & 63, w = threadIdx.x >> 6;
  int d = dq * 4 + w;                   // < 50000 exactly

  float adq = adst[d * 4 + q];
  float ex = __expf(lrelu02(asrc[d * 4 + q] + adq));
  float den = ex;
  const _Float16* hb = hH + q * 64 + lane;
  float acc = ex * (float)hb[(size_t)d * 256];

  const float* eq = exfh + (size_t)q * EDGES;
  int e0 = row_ptr[d], e1 = row_ptr[d + 1];
  int e = e0;
  for (; e < e1 && (e & 3); e++){
    float ee = eq[e];
    den += ee; acc += ee * (float)hb[(size_t)col[e] * 256];
  }
  for (; e + 8 <= e1; e += 8){
    int4 cA = *(const int4*)&col[e];
    int4 cB = *(const int4*)&col[e + 4];
    float4 eA = *(const float4*)&eq[e];
    float4 eB = *(const float4*)&eq[e + 4];
    float v0 = (float)hb[(size_t)cA.x * 256];
    float v1 = (float)hb[(size_t)cA.y * 256];
    float v2 = (float)hb[(size_t)cA.z * 256];
    float v3 = (float)hb[(size_t)cA.w * 256];
    float v4 = (float)hb[(size_t)cB.x * 256];
    float v5 = (float)hb[(size_t)cB.y * 256];
    float v6 = (float)hb[(size_t)cB.z * 256];
    float v7 = (float)hb[(size_t)cB.w * 256];
    den += eA.x + eA.y + eA.z + eA.w + eB.x + eB.y + eB.z + eB.w;
    acc += eA.x * v0 + eA.y * v1 + eA.z * v2 + eA.w * v3
         + eB.x * v4 + eB.y * v5 + eB.z * v6 + eB.w * v7;
  }
  for (; e < e1; e++){
    float ee = eq[e];
    den += ee; acc += ee * (float)hb[(size_t)col[e] * 256];
  }

  int cc = q * 64 + lane;
  float o = acc / (den + 1e-16f) + bias[cc];
  o = o > 0.f ? o : expm1f(o);
  out[(size_t)d * 256 + cc] = (_Float16)o;
}

// ---------------- layer-2 aggregate (1 head, 64ch), fused exp, unroll 8 ----------------

__global__ __launch_bounds__(256) void gat_aggregate1(const _Float16* __restrict__ hH, const float* __restrict__ asrc,
                                                       const float* __restrict__ adst,
                                                       const int* __restrict__ row_ptr, const int* __restrict__ col,
                                                       const float* __restrict__ bias, float* __restrict__ out){
  int lane = threadIdx.x & 63;
  int wid = threadIdx.x >> 6;
  int d = blockIdx.x * 4 + wid;
  if (d >= NODES) return;

  float adq = adst[d];
  float ex = __expf(lrelu02(asrc[d] + adq));
  float acc = ex * (float)hH[(size_t)d * 64 + lane];
  float den = ex;

  int e0 = row_ptr[d], e1 = row_ptr[d + 1];
  const _Float16* hbase = hH + lane;
  int e = e0;
  for (; e < e1 && (e & 3); e++){
    int s0 = col[e];
    float x0 = __expf(lrelu02(asrc[s0] + adq));
    den += x0;
    acc += x0 * (float)hbase[(size_t)s0 * 64];
  }
  for (; e + 8 <= e1; e += 8){
    int4 cA = *(const int4*)&col[e];
    int4 cB = *(const int4*)&col[e + 4];
    float a0 = asrc[cA.x], a1 = asrc[cA.y], a2 = asrc[cA.z], a3 = asrc[cA.w];
    float a4 = asrc[cB.x], a5 = asrc[cB.y], a6 = asrc[cB.z], a7 = asrc[cB.w];
    float v0 = (float)hbase[(size_t)cA.x * 64];
    float v1 = (float)hbase[(size_t)cA.y * 64];
    float v2 = (float)hbase[(size_t)cA.z * 64];
    float v3 = (float)hbase[(size_t)cA.w * 64];
    float v4 = (float)hbase[(size_t)cB.x * 64];
    float v5 = (float)hbase[(size_t)cB.y * 64];
    float v6 = (float)hbase[(size_t)cB.z * 64];
    float v7 = (float)hbase[(size_t)cB.w * 64];
    float x0 = __expf(lrelu02(a0 + adq)), x1 = __expf(lrelu02(a1 + adq));
    float x2 = __expf(lrelu02(a2 + adq)), x3 = __expf(lrelu02(a3 + adq));
    float x4 = __expf(lrelu02(a4 + adq)), x5 = __expf(lrelu02(a5 + adq));
    float x6 = __expf(lrelu02(a6 + adq)), x7 = __expf(lrelu02(a7 + adq));
    den += x0 + x1 + x2 + x3 + x4 + x5 + x6 + x7;
    acc += x0 * v0 + x1 * v1 + x2 * v2 + x3 * v3 + x4 * v4 + x5 * v5 + x6 * v6 + x7 * v7;
  }
  for (; e < e1; e++){
    int s0 = col[e];
    float x0 = __expf(lrelu02(asrc[s0] + adq));
    den += x0;
    acc += x0 * (float)hbase[(size_t)s0 * 64];
  }
  out[(size_t)d * 64 + lane] = acc / (den + 1e-16f) + bias[lane];
}

// ---------------- launch ----------------

extern "C" void kernel_launch(void* const* d_in, const int* in_sizes, int n_in,
                              void* d_out, int out_size, void* d_ws, size_t ws_size,
                              hipStream_t stream) {
  const float* x   = (const float*)d_in[0];
  const int*   ei  = (const int*)  d_in[1];
  const float* W0  = (const float*)d_in[2];
  const float* as0 = (const float*)d_in[3];
  const float* ad0 = (const float*)d_in[4];
  const float* b0  = (const float*)d_in[5];
  const float* W1  = (const float*)d_in[6];
  const float* as1 = (const float*)d_in[7];
  const float* ad1 = (const float*)d_in[8];
  const float* b1  = (const float*)d_in[9];
  const float* W2  = (const float*)d_in[10];
  const float* as2 = (const float*)d_in[11];
  const float* ad2 = (const float*)d_in[12];
  const float* b2  = (const float*)d_in[13];
  float* out = (float*)d_out;

  auto al = [](size_t v){ return (v + 255) & ~(size_t)255; };
  char* p = (char*)d_ws;
  int*      row_ptr = (int*)p;      p += al((NODES + 1) * sizeof(int));
  int*      cnt     = (int*)p;      p += al(NODES * sizeof(int));
  int*      bsums   = (int*)p;      p += al(64 * sizeof(int));
  int*      col     = (int*)p;      p += al(EDGES * sizeof(int));
  int*      dstarr  = (int*)p;      p += al(EDGES * sizeof(int));
  float*    exf     = (float*)p;    p += al((size_t)EDGES * 4 * sizeof(float));   // L0 interleaved / L1 head-major
  float*    asrc    = (float*)p;    p += al(NODES * 4 * sizeof(float));
  float*    adst    = (float*)p;    p += al(NODES * 4 * sizeof(float));
  _Float16* xh      = (_Float16*)p; p += al((size_t)NODES * 64 * sizeof(_Float16));
  _Float16* hH      = (_Float16*)p; p += al((size_t)NODES * 256 * sizeof(_Float16));
  _Float16* actb    = (_Float16*)p; p += al((size_t)NODES * 256 * sizeof(_Float16));
  _Float16* Wt0     = (_Float16*)p; p += al(256 * 64 * sizeof(_Float16));
  _Float16* Wt1     = (_Float16*)p; p += al(256 * 256 * sizeof(_Float16));
  _Float16* Wt2     = (_Float16*)p; p += al(64 * 256 * sizeof(_Float16));
  float*    ws0     = (float*)p;    p += al(256 * sizeof(float));
  float*    wd0     = (float*)p;    p += al(256 * sizeof(float));

  // ---- prep ----
  gat_cvt_h<<<(NODES * 64 / 4 + 255) / 256, 256, 0, stream>>>(x, xh, NODES * 64 / 4);
  gat_wt<<<dim3(1, 64), 256, 0, stream>>>(W0, Wt0, 64, 256);
  gat_wt<<<dim3(1, 256), 256, 0, stream>>>(W1, Wt1, 256, 256);
  gat_wt<<<dim3(1, 256), 256, 0, stream>>>(W2, Wt2, 256, 64);
  gat_ws0<<<1, 256, 0, stream>>>(W0, as0, ad0, ws0, wd0);

  // ---- CSR build (by dst) ----
  gat_zero<<<(NODES + 255) / 256, 256, 0, stream>>>(cnt, NODES);
  gat_hist<<<(EDGES + 255) / 256, 256, 0, stream>>>(ei, cnt);
  gat_blocksum<<<NB_SCAN, 256, 0, stream>>>(cnt, bsums);
  gat_scan_bsums<<<1, 64, 0, stream>>>(bsums, NB_SCAN);
  gat_rowptr<<<NB_SCAN, 256, 0, stream>>>(cnt, bsums, row_ptr);
  gat_scatter<<<(EDGES + 255) / 256, 256, 0, stream>>>(ei, row_ptr, cnt, col, dstarr);

  const int nodeBlocks = (NODES + 3) / 4;
  const int gemmBlocks = (NODES + 63) / 64;
  const int edgeBlocks = (EDGES + 255) / 256;

  // ---- Layer 0 (swapped): attn in input space, edge exps, aggregate x, block-diag GEMM + bias + ELU ----
  gat_attn0<<<nodeBlocks, 256, 0, stream>>>(xh, ws0, wd0, asrc, adst, NODES);
  gat_edge_exp0<<<edgeBlocks, 256, 0, stream>>>(col, dstarr, asrc, adst, exf);
  gat_aggregate_in64<<<nodeBlocks, 256, 0, stream>>>(xh, exf, asrc, adst, row_ptr, col, hH);
  gat_gemm_bd<<<gemmBlocks, 256, 0, stream>>>(hH, Wt0, b0, actb, NODES);

  // ---- Layer 1: actb @ W1 -> hH; attn; edge exps (head-major); head-pinned aggregate ----
  gat_gemm_mfma<256, 256><<<gemmBlocks, 256, 0, stream>>>(actb, Wt1, hH, NODES);
  gat_attn4<<<nodeBlocks, 256, 0, stream>>>(hH, as1, ad1, asrc, adst, NODES);
  gat_edge_exp4h<<<edgeBlocks, 256, 0, stream>>>(col, dstarr, asrc, adst, exf);
  gat_aggregate4h<<<NODES, 256, 0, stream>>>(hH, exf, asrc, adst, row_ptr, col, b1, actb);

  // ---- Layer 2: actb @ W2 -> hH (64ch); attn; aggregate ----
  gat_gemm_mfma<256, 64><<<gemmBlocks, 256, 0, stream>>>(actb, Wt2, hH, NODES);
  gat_attn1<<<nodeBlocks, 256, 0, stream>>>(hH, as2, ad2, asrc, adst, NODES);
  gat_aggregate1<<<nodeBlocks, 256, 0, stream>>>(hH, asrc, adst, row_ptr, col, b2, out);
}

// Round 7
// 373.386 us; speedup vs baseline: 1.2823x; 1.2823x over previous
//
#include <hip/hip_runtime.h>
#include <hip/hip_fp16.h>
#include <math.h>

#define NODES 50000
#define EDGES 800000
#define NB_SCAN ((NODES + 1023) / 1024)

typedef __attribute__((ext_vector_type(8))) _Float16 f16x8;
typedef __attribute__((ext_vector_type(4))) _Float16 f16x4;
typedef __attribute__((ext_vector_type(4))) float f32x4;

__device__ __forceinline__ float lrelu02(float x){ return x > 0.f ? x : 0.2f * x; }

__device__ __forceinline__ f32x4 shflx4(f32x4 v, int m){
  f32x4 r;
  r[0] = __shfl_xor(v[0], m); r[1] = __shfl_xor(v[1], m);
  r[2] = __shfl_xor(v[2], m); r[3] = __shfl_xor(v[3], m);
  return r;
}

// ---------------- CSR build ----------------

__global__ __launch_bounds__(256) void gat_zero(int* __restrict__ p, int n){
  int i = blockIdx.x * 256 + threadIdx.x;
  if (i < n) p[i] = 0;
}

__global__ __launch_bounds__(256) void gat_hist(const int* __restrict__ ei, int* __restrict__ cnt){
  int e = blockIdx.x * 256 + threadIdx.x;
  if (e < EDGES) atomicAdd(&cnt[ei[EDGES + e]], 1);
}

__global__ __launch_bounds__(256) void gat_blocksum(const int* __restrict__ cnt, int* __restrict__ bsums){
  __shared__ int sd[256];
  int t = threadIdx.x, b = blockIdx.x;
  int base = b * 1024 + t * 4, s = 0;
  #pragma unroll
  for (int j = 0; j < 4; j++){ int i = base + j; if (i < NODES) s += cnt[i]; }
  sd[t] = s; __syncthreads();
  for (int o = 128; o > 0; o >>= 1){ if (t < o) sd[t] += sd[t + o]; __syncthreads(); }
  if (t == 0) bsums[b] = sd[0];
}

__global__ void gat_scan_bsums(int* bsums, int nb){
  if (threadIdx.x == 0 && blockIdx.x == 0){
    int run = 0;
    for (int i = 0; i < nb; i++){ int v = bsums[i]; bsums[i] = run; run += v; }
  }
}

__global__ __launch_bounds__(256) void gat_rowptr(int* __restrict__ cnt, const int* __restrict__ bsums,
                                                  int* __restrict__ row_ptr){
  __shared__ int sd[256];
  int t = threadIdx.x, b = blockIdx.x;
  int base = b * 1024 + t * 4;
  int c[4]; int s = 0;
  #pragma unroll
  for (int j = 0; j < 4; j++){
    int i = base + j;
    c[j] = (i < NODES) ? cnt[i] : 0;
    s += c[j];
    if (i < NODES) cnt[i] = 0;
  }
  sd[t] = s; __syncthreads();
  for (int o = 1; o < 256; o <<= 1){
    int v = (t >= o) ? sd[t - o] : 0;
    __syncthreads();
    if (t >= o) sd[t] += v;
    __syncthreads();
  }
  int off = bsums[b] + sd[t] - s;
  #pragma unroll
  for (int j = 0; j < 4; j++){
    int i = base + j;
    if (i < NODES){ row_ptr[i] = off; off += c[j]; }
  }
  if (b == 0 && t == 0) row_ptr[NODES] = EDGES;
}

__global__ __launch_bounds__(256) void gat_scatter(const int* __restrict__ ei, const int* __restrict__ row_ptr,
                                                    int* __restrict__ fill, int* __restrict__ col,
                                                    int* __restrict__ dstarr){
  int e = blockIdx.x * 256 + threadIdx.x;
  if (e < EDGES){
    int s = ei[e], d = ei[EDGES + e];
    int pos = row_ptr[d] + atomicAdd(&fill[d], 1);
    col[pos] = s;
    dstarr[pos] = d;
  }
}

// ---------------- fp32 -> fp16 convert / W transposes (fused) ----------------

__global__ __launch_bounds__(256) void gat_cvt_h(const float* __restrict__ src, _Float16* __restrict__ dst, int n4){
  int i = blockIdx.x * 256 + threadIdx.x;
  if (i < n4){
    float4 v = *(const float4*)(src + (size_t)i * 4);
    f16x4 h = { (_Float16)v.x, (_Float16)v.y, (_Float16)v.z, (_Float16)v.w };
    *(f16x4*)(dst + (size_t)i * 4) = h;
  }
}

// grid = 576 blocks: k 0..63 -> Wt0, 64..319 -> Wt1, 320..575 -> Wt2
__global__ __launch_bounds__(256) void gat_wt_all(const float* __restrict__ W0, const float* __restrict__ W1,
                                                  const float* __restrict__ W2,
                                                  _Float16* __restrict__ Wt0, _Float16* __restrict__ Wt1,
                                                  _Float16* __restrict__ Wt2){
  int n = threadIdx.x;
  int k = blockIdx.x;
  if (k < 64){
    Wt0[(size_t)n * 64 + k] = (_Float16)W0[(size_t)k * 256 + n];
  } else if (k < 320){
    int kk = k - 64;
    Wt1[(size_t)n * 256 + kk] = (_Float16)W1[(size_t)kk * 256 + n];
  } else {
    int kk = k - 320;
    if (n < 64) Wt2[(size_t)n * 256 + kk] = (_Float16)W2[(size_t)kk * 64 + n];
  }
}

// ws[h*64+c] = sum_cc W0[c][h*64+cc]*a_src0[h][cc]
__global__ __launch_bounds__(256) void gat_ws0(const float* __restrict__ W0, const float* __restrict__ a_src0,
                                               const float* __restrict__ a_dst0,
                                               float* __restrict__ ws, float* __restrict__ wd){
  int t = threadIdx.x;
  int h = t >> 6, c = t & 63;
  float s = 0.f, d = 0.f;
  for (int cc = 0; cc < 64; cc++){
    float w = W0[(size_t)c * 256 + h * 64 + cc];
    s += w * a_src0[h * 64 + cc];
    d += w * a_dst0[h * 64 + cc];
  }
  ws[h * 64 + c] = s;
  wd[h * 64 + c] = d;
}

// ---------------- MFMA fp16 GEMM: C[M,N] = A[M,K] @ W[K,N], Wt = W^T [N][K] ----------------

template<int K, int N>
__global__ __launch_bounds__(256) void gat_gemm_mfma(const _Float16* __restrict__ A, const _Float16* __restrict__ Wt,
                                                      _Float16* __restrict__ C, int M){
  constexpr int NT = N / 64;
  constexpr int LDT = 40;
  __shared__ _Float16 As[64][LDT];
  __shared__ _Float16 Bs[N][LDT];

  int tid = threadIdx.x;
  int w = tid >> 6, l = tid & 63;
  int lg = l >> 4, lr = l & 15;
  int bm = blockIdx.x * 64;

  f32x4 acc[4][NT];
  #pragma unroll
  for (int m = 0; m < 4; m++)
    #pragma unroll
    for (int n = 0; n < NT; n++)
      acc[m][n] = (f32x4){0.f, 0.f, 0.f, 0.f};

  int ar = tid >> 2;
  int akc = (tid & 3) * 8;
  bool avalid = (bm + ar) < M;
  const _Float16* aptr = A + (size_t)(bm + ar) * K + akc;

  for (int k0 = 0; k0 < K; k0 += 32){
    float4 av = avalid ? *(const float4*)(aptr + k0) : make_float4(0.f, 0.f, 0.f, 0.f);
    __syncthreads();
    *(float4*)&As[ar][akc] = av;
    #pragma unroll
    for (int c = 0; c < N / 64; c++){
      int idx = c * 256 + tid;
      int n = idx >> 2, kc = (idx & 3) * 8;
      *(float4*)&Bs[n][kc] = *(const float4*)(Wt + (size_t)n * K + k0 + kc);
    }
    __syncthreads();

    f16x8 af[4], bf[NT];
    #pragma unroll
    for (int m = 0; m < 4; m++) af[m] = *(const f16x8*)&As[16 * m + lr][8 * lg];
    #pragma unroll
    for (int n = 0; n < NT; n++) bf[n] = *(const f16x8*)&Bs[w * (N / 4) + 16 * n + lr][8 * lg];
    #pragma unroll
    for (int m = 0; m < 4; m++)
      #pragma unroll
      for (int n = 0; n < NT; n++)
        acc[m][n] = __builtin_amdgcn_mfma_f32_16x16x32_f16(af[m], bf[n], acc[m][n], 0, 0, 0);
  }

  #pragma unroll
  for (int m = 0; m < 4; m++){
    #pragma unroll
    for (int j = 0; j < 4; j++){
      int row = bm + 16 * m + 4 * lg + j;
      if (row < M){
        #pragma unroll
        for (int n = 0; n < NT; n++)
          C[(size_t)row * N + w * (N / 4) + 16 * n + lr] = (_Float16)acc[m][n][j];
      }
    }
  }
}

// ---------------- block-diagonal per-head GEMM (layer 0 post-aggregate), no LDS ----------------

__global__ __launch_bounds__(256) void gat_gemm_bd(const _Float16* __restrict__ A, const _Float16* __restrict__ Bt,
                                                    const float* __restrict__ bias, _Float16* __restrict__ C, int M){
  int tid = threadIdx.x;
  int w = tid >> 6, l = tid & 63;
  int lg = l >> 4, lr = l & 15;
  int bm = blockIdx.x * 64;

  f32x4 acc[4][4];
  #pragma unroll
  for (int m = 0; m < 4; m++)
    #pragma unroll
    for (int n = 0; n < 4; n++)
      acc[m][n] = (f32x4){0.f, 0.f, 0.f, 0.f};

  f16x8 zf = {};
  #pragma unroll
  for (int ks = 0; ks < 2; ks++){
    int koff = ks * 32;
    f16x8 af[4], bf[4];
    #pragma unroll
    for (int m = 0; m < 4; m++){
      int row = bm + 16 * m + lr;
      af[m] = (row < M) ? *(const f16x8*)(A + (size_t)row * 256 + w * 64 + koff + 8 * lg) : zf;
    }
    #pragma unroll
    for (int n = 0; n < 4; n++)
      bf[n] = *(const f16x8*)(Bt + (size_t)(w * 64 + 16 * n + lr) * 64 + koff + 8 * lg);
    #pragma unroll
    for (int m = 0; m < 4; m++)
      #pragma unroll
      for (int n = 0; n < 4; n++)
        acc[m][n] = __builtin_amdgcn_mfma_f32_16x16x32_f16(af[m], bf[n], acc[m][n], 0, 0, 0);
  }

  #pragma unroll
  for (int m = 0; m < 4; m++){
    #pragma unroll
    for (int j = 0; j < 4; j++){
      int row = bm + 16 * m + 4 * lg + j;
      if (row < M){
        #pragma unroll
        for (int n = 0; n < 4; n++){
          int cc = w * 64 + 16 * n + lr;
          float o = acc[m][n][j] + bias[cc];
          o = o > 0.f ? o : expm1f(o);
          C[(size_t)row * 256 + cc] = (_Float16)o;
        }
      }
    }
  }
}

// ---------------- attention coefficients ----------------

__global__ __launch_bounds__(256) void gat_attn0(const _Float16* __restrict__ xh, const float* __restrict__ ws,
                                                  const float* __restrict__ wd,
                                                  float* __restrict__ asrc, float* __restrict__ adst, int N){
  int lane = threadIdx.x & 63;
  int wid = threadIdx.x >> 6;
  int n = blockIdx.x * 4 + wid;
  if (n >= N) return;
  float v = (float)xh[(size_t)n * 64 + lane];
  #pragma unroll
  for (int h = 0; h < 4; h++){
    float s1 = v * ws[h * 64 + lane];
    float s2 = v * wd[h * 64 + lane];
    #pragma unroll
    for (int o = 32; o > 0; o >>= 1){ s1 += __shfl_xor(s1, o); s2 += __shfl_xor(s2, o); }
    if (lane == 0){ asrc[n * 4 + h] = s1; adst[n * 4 + h] = s2; }
  }
}

// 4-head, 256ch: lane owns 4 channels of one head; 16-lane-group reduction
__global__ __launch_bounds__(256) void gat_attn4(const _Float16* __restrict__ h, const float* __restrict__ a_src,
                                                  const float* __restrict__ a_dst,
                                                  float* __restrict__ asrc, float* __restrict__ adst, int N){
  int lane = threadIdx.x & 63;
  int wid = threadIdx.x >> 6;
  int n = blockIdx.x * 4 + wid;
  if (n >= N) return;
  int co = lane * 4;
  f16x4 hv = *(const f16x4*)(h + (size_t)n * 256 + co);
  float4 av = *(const float4*)&a_src[co];
  float4 dv = *(const float4*)&a_dst[co];
  float f0 = (float)hv[0], f1 = (float)hv[1], f2 = (float)hv[2], f3 = (float)hv[3];
  float s1 = f0 * av.x + f1 * av.y + f2 * av.z + f3 * av.w;
  float s2 = f0 * dv.x + f1 * dv.y + f2 * dv.z + f3 * dv.w;
  #pragma unroll
  for (int o = 8; o > 0; o >>= 1){ s1 += __shfl_xor(s1, o); s2 += __shfl_xor(s2, o); }
  if ((lane & 15) == 0){
    int q = lane >> 4;
    asrc[n * 4 + q] = s1;
    adst[n * 4 + q] = s2;
  }
}

__global__ __launch_bounds__(256) void gat_attn1(const _Float16* __restrict__ h, const float* __restrict__ a_src,
                                                  const float* __restrict__ a_dst,
                                                  float* __restrict__ asrc, float* __restrict__ adst, int N){
  int lane = threadIdx.x & 63;
  int wid = threadIdx.x >> 6;
  int n = blockIdx.x * 4 + wid;
  if (n >= N) return;
  float v = (float)h[(size_t)n * 64 + lane];
  float s1 = v * a_src[lane];
  float s2 = v * a_dst[lane];
  #pragma unroll
  for (int o = 32; o > 0; o >>= 1){ s1 += __shfl_xor(s1, o); s2 += __shfl_xor(s2, o); }
  if (lane == 0){ asrc[n] = s1; adst[n] = s2; }
}

// ---------------- edge exp precompute ----------------

// layer 0: interleaved exf[e][4]
__global__ __launch_bounds__(256) void gat_edge_exp0(const int* __restrict__ col, const int* __restrict__ dstarr,
                                                      const float* __restrict__ asrc, const float* __restrict__ adst,
                                                      float* __restrict__ exf){
  int i = blockIdx.x * 256 + threadIdx.x;
  if (i >= EDGES) return;
  int s = col[i], d = dstarr[i];
  float4 a = *(const float4*)&asrc[s * 4];
  float4 b = *(const float4*)&adst[d * 4];
  float4 r;
  r.x = __expf(lrelu02(a.x + b.x));
  r.y = __expf(lrelu02(a.y + b.y));
  r.z = __expf(lrelu02(a.z + b.z));
  r.w = __expf(lrelu02(a.w + b.w));
  *(float4*)&exf[(size_t)i * 4] = r;
}

// layer 2: scalar exf1[e]
__global__ __launch_bounds__(256) void gat_edge_exp1h(const int* __restrict__ col, const int* __restrict__ dstarr,
                                                       const float* __restrict__ asrc, const float* __restrict__ adst,
                                                       float* __restrict__ exf1){
  int i = blockIdx.x * 256 + threadIdx.x;
  if (i >= EDGES) return;
  exf1[i] = __expf(lrelu02(asrc[col[i]] + adst[dstarr[i]]));
}

// ---------------- layer-0 aggregate in 64-dim input space ----------------
// wave = 4 edge-slots x 16 lanes; lane loads f16x4 (8B) of one edge's row; shfl-reduce over slots.

__global__ __launch_bounds__(256) void gat_aggregate_in64(const _Float16* __restrict__ xh, const float* __restrict__ exf,
                                                           const float* __restrict__ asrc, const float* __restrict__ adst,
                                                           const int* __restrict__ row_ptr, const int* __restrict__ col,
                                                           _Float16* __restrict__ agg){
  int lane = threadIdx.x & 63;
  int wid = threadIdx.x >> 6;
  int d = blockIdx.x * 4 + wid;
  if (d >= NODES) return;
  int slot = lane >> 4;
  int cpos = (lane & 15) * 4;

  f32x4 acc0 = {0,0,0,0}, acc1 = {0,0,0,0}, acc2 = {0,0,0,0}, acc3 = {0,0,0,0};
  f32x4 den = {0,0,0,0};

  int e0 = row_ptr[d], e1 = row_ptr[d + 1];
  const _Float16* xb = xh + cpos;
  int e = e0;
  for (; e + 8 <= e1; e += 8){
    int eA = e + slot, eB = e + 4 + slot;
    int sA = col[eA], sB = col[eB];
    float4 fA = *(const float4*)(exf + (size_t)eA * 4);
    float4 fB = *(const float4*)(exf + (size_t)eB * 4);
    f16x4 hA = *(const f16x4*)(xb + (size_t)sA * 64);
    f16x4 hB = *(const f16x4*)(xb + (size_t)sB * 64);
    f32x4 vA = { (float)hA[0], (float)hA[1], (float)hA[2], (float)hA[3] };
    f32x4 vB = { (float)hB[0], (float)hB[1], (float)hB[2], (float)hB[3] };
    den += (f32x4){ fA.x + fB.x, fA.y + fB.y, fA.z + fB.z, fA.w + fB.w };
    acc0 += fA.x * vA + fB.x * vB;
    acc1 += fA.y * vA + fB.y * vB;
    acc2 += fA.z * vA + fB.z * vB;
    acc3 += fA.w * vA + fB.w * vB;
  }
  if (e + 4 <= e1){
    int eA = e + slot;
    int sA = col[eA];
    float4 fA = *(const float4*)(exf + (size_t)eA * 4);
    f16x4 hA = *(const f16x4*)(xb + (size_t)sA * 64);
    f32x4 vA = { (float)hA[0], (float)hA[1], (float)hA[2], (float)hA[3] };
    den += (f32x4){ fA.x, fA.y, fA.z, fA.w };
    acc0 += fA.x * vA; acc1 += fA.y * vA; acc2 += fA.z * vA; acc3 += fA.w * vA;
    e += 4;
  }
  {
    int eA = e + slot;
    if (eA < e1){
      int sA = col[eA];
      float4 fA = *(const float4*)(exf + (size_t)eA * 4);
      f16x4 hA = *(const f16x4*)(xb + (size_t)sA * 64);
      f32x4 vA = { (float)hA[0], (float)hA[1], (float)hA[2], (float)hA[3] };
      den += (f32x4){ fA.x, fA.y, fA.z, fA.w };
      acc0 += fA.x * vA; acc1 += fA.y * vA; acc2 += fA.z * vA; acc3 += fA.w * vA;
    }
  }

  // reduce across the 4 slots (xor 16, 32)
  #pragma unroll
  for (int off = 16; off <= 32; off <<= 1){
    acc0 += shflx4(acc0, off);
    acc1 += shflx4(acc1, off);
    acc2 += shflx4(acc2, off);
    acc3 += shflx4(acc3, off);
    den  += shflx4(den,  off);
  }

  // self loop (all lanes compute identically per cpos -> copies stay consistent)
  float4 a4 = *(const float4*)&asrc[d * 4];
  float4 b4 = *(const float4*)&adst[d * 4];
  float es0 = __expf(lrelu02(a4.x + b4.x));
  float es1 = __expf(lrelu02(a4.y + b4.y));
  float es2 = __expf(lrelu02(a4.z + b4.z));
  float es3 = __expf(lrelu02(a4.w + b4.w));
  f16x4 hs = *(const f16x4*)(xh + (size_t)d * 64 + cpos);
  f32x4 vs = { (float)hs[0], (float)hs[1], (float)hs[2], (float)hs[3] };
  acc0 += es0 * vs; acc1 += es1 * vs; acc2 += es2 * vs; acc3 += es3 * vs;
  den += (f32x4){ es0, es1, es2, es3 };

  if (slot == 0){
    float i0 = 1.f / (den[0] + 1e-16f), i1 = 1.f / (den[1] + 1e-16f);
    float i2 = 1.f / (den[2] + 1e-16f), i3 = 1.f / (den[3] + 1e-16f);
    _Float16* ob = agg + (size_t)d * 256 + cpos;
    f16x4 o0 = { (_Float16)(acc0[0]*i0), (_Float16)(acc0[1]*i0), (_Float16)(acc0[2]*i0), (_Float16)(acc0[3]*i0) };
    f16x4 o1 = { (_Float16)(acc1[0]*i1), (_Float16)(acc1[1]*i1), (_Float16)(acc1[2]*i1), (_Float16)(acc1[3]*i1) };
    f16x4 o2 = { (_Float16)(acc2[0]*i2), (_Float16)(acc2[1]*i2), (_Float16)(acc2[2]*i2), (_Float16)(acc2[3]*i2) };
    f16x4 o3 = { (_Float16)(acc3[0]*i3), (_Float16)(acc3[1]*i3), (_Float16)(acc3[2]*i3), (_Float16)(acc3[3]*i3) };
    *(f16x4*)(ob)       = o0;
    *(f16x4*)(ob + 64)  = o1;
    *(f16x4*)(ob + 128) = o2;
    *(f16x4*)(ob + 192) = o3;
  }
}

// ---------------- layer-1 aggregate (4 heads, 256ch), fused exp, unroll 8 (round-5 structure) ----------------

__global__ __launch_bounds__(256) void gat_aggregate4(const _Float16* __restrict__ hH, const float* __restrict__ asrc,
                                                       const float* __restrict__ adst,
                                                       const int* __restrict__ row_ptr, const int* __restrict__ col,
                                                       const float* __restrict__ bias, _Float16* __restrict__ out){
  int lane = threadIdx.x & 63;
  int wid = threadIdx.x >> 6;
  int d = blockIdx.x * 4 + wid;
  if (d >= NODES) return;
  int q = lane >> 4;
  int co = lane * 4;

  float adq = adst[d * 4 + q];

  float ex = __expf(lrelu02(asrc[d * 4 + q] + adq));
  f16x4 hv = *(const f16x4*)(hH + (size_t)d * 256 + co);
  float4 acc = make_float4(ex * (float)hv[0], ex * (float)hv[1], ex * (float)hv[2], ex * (float)hv[3]);
  float den = ex;

  int e0 = row_ptr[d], e1 = row_ptr[d + 1];
  const _Float16* hbase = hH + co;
  int e = e0;
  for (; e < e1 && (e & 3); e++){
    int s0 = col[e];
    float a0 = asrc[s0 * 4 + q];
    f16x4 h0 = *(const f16x4*)(hbase + (size_t)s0 * 256);
    float x0 = __expf(lrelu02(a0 + adq));
    den += x0;
    acc.x += x0 * (float)h0[0]; acc.y += x0 * (float)h0[1];
    acc.z += x0 * (float)h0[2]; acc.w += x0 * (float)h0[3];
  }
  for (; e + 8 <= e1; e += 8){
    int4 cA = *(const int4*)&col[e];
    int4 cB = *(const int4*)&col[e + 4];
    float a0 = asrc[cA.x * 4 + q], a1 = asrc[cA.y * 4 + q], a2 = asrc[cA.z * 4 + q], a3 = asrc[cA.w * 4 + q];
    float a4 = asrc[cB.x * 4 + q], a5 = asrc[cB.y * 4 + q], a6 = asrc[cB.z * 4 + q], a7 = asrc[cB.w * 4 + q];
    f16x4 h0 = *(const f16x4*)(hbase + (size_t)cA.x * 256);
    f16x4 h1 = *(const f16x4*)(hbase + (size_t)cA.y * 256);
    f16x4 h2 = *(const f16x4*)(hbase + (size_t)cA.z * 256);
    f16x4 h3 = *(const f16x4*)(hbase + (size_t)cA.w * 256);
    f16x4 h4 = *(const f16x4*)(hbase + (size_t)cB.x * 256);
    f16x4 h5 = *(const f16x4*)(hbase + (size_t)cB.y * 256);
    f16x4 h6 = *(const f16x4*)(hbase + (size_t)cB.z * 256);
    f16x4 h7 = *(const f16x4*)(hbase + (size_t)cB.w * 256);
    float x0 = __expf(lrelu02(a0 + adq)), x1 = __expf(lrelu02(a1 + adq));
    float x2 = __expf(lrelu02(a2 + adq)), x3 = __expf(lrelu02(a3 + adq));
    float x4 = __expf(lrelu02(a4 + adq)), x5 = __expf(lrelu02(a5 + adq));
    float x6 = __expf(lrelu02(a6 + adq)), x7 = __expf(lrelu02(a7 + adq));
    den += x0 + x1 + x2 + x3 + x4 + x5 + x6 + x7;
    acc.x += x0 * (float)h0[0] + x1 * (float)h1[0] + x2 * (float)h2[0] + x3 * (float)h3[0]
           + x4 * (float)h4[0] + x5 * (float)h5[0] + x6 * (float)h6[0] + x7 * (float)h7[0];
    acc.y += x0 * (float)h0[1] + x1 * (float)h1[1] + x2 * (float)h2[1] + x3 * (float)h3[1]
           + x4 * (float)h4[1] + x5 * (float)h5[1] + x6 * (float)h6[1] + x7 * (float)h7[1];
    acc.z += x0 * (float)h0[2] + x1 * (float)h1[2] + x2 * (float)h2[2] + x3 * (float)h3[2]
           + x4 * (float)h4[2] + x5 * (float)h5[2] + x6 * (float)h6[2] + x7 * (float)h7[2];
    acc.w += x0 * (float)h0[3] + x1 * (float)h1[3] + x2 * (float)h2[3] + x3 * (float)h3[3]
           + x4 * (float)h4[3] + x5 * (float)h5[3] + x6 * (float)h6[3] + x7 * (float)h7[3];
  }
  for (; e < e1; e++){
    int s0 = col[e];
    float a0 = asrc[s0 * 4 + q];
    f16x4 h0 = *(const f16x4*)(hbase + (size_t)s0 * 256);
    float x0 = __expf(lrelu02(a0 + adq));
    den += x0;
    acc.x += x0 * (float)h0[0]; acc.y += x0 * (float)h0[1];
    acc.z += x0 * (float)h0[2]; acc.w += x0 * (float)h0[3];
  }

  float inv = 1.f / (den + 1e-16f);
  float4 b4 = *(const float4*)&bias[co];
  float4 o = make_float4(acc.x * inv + b4.x, acc.y * inv + b4.y, acc.z * inv + b4.z, acc.w * inv + b4.w);
  o.x = o.x > 0.f ? o.x : expm1f(o.x);
  o.y = o.y > 0.f ? o.y : expm1f(o.y);
  o.z = o.z > 0.f ? o.z : expm1f(o.z);
  o.w = o.w > 0.f ? o.w : expm1f(o.w);
  f16x4 oh = { (_Float16)o.x, (_Float16)o.y, (_Float16)o.z, (_Float16)o.w };
  *(f16x4*)(out + (size_t)d * 256 + co) = oh;
}

// ---------------- layer-2 aggregate (1 head, 64ch): 4 edge-slots x 16 lanes, 8B gathers ----------------

__global__ __launch_bounds__(256) void gat_aggregate1n(const _Float16* __restrict__ hH, const float* __restrict__ exf1,
                                                        const float* __restrict__ asrc, const float* __restrict__ adst,
                                                        const int* __restrict__ row_ptr, const int* __restrict__ col,
                                                        const float* __restrict__ bias, float* __restrict__ out){
  int lane = threadIdx.x & 63;
  int wid = threadIdx.x >> 6;
  int d = blockIdx.x * 4 + wid;
  if (d >= NODES) return;
  int slot = lane >> 4;
  int cpos = (lane & 15) * 4;

  f32x4 acc = {0,0,0,0};
  float den = 0.f;

  int e0 = row_ptr[d], e1 = row_ptr[d + 1];
  const _Float16* hb = hH + cpos;
  int e = e0;
  for (; e + 8 <= e1; e += 8){
    int eA = e + slot, eB = e + 4 + slot;
    int sA = col[eA], sB = col[eB];
    float fA = exf1[eA], fB = exf1[eB];
    f16x4 hA = *(const f16x4*)(hb + (size_t)sA * 64);
    f16x4 hB = *(const f16x4*)(hb + (size_t)sB * 64);
    f32x4 vA = { (float)hA[0], (float)hA[1], (float)hA[2], (float)hA[3] };
    f32x4 vB = { (float)hB[0], (float)hB[1], (float)hB[2], (float)hB[3] };
    den += fA + fB;
    acc += fA * vA + fB * vB;
  }
  if (e + 4 <= e1){
    int eA = e + slot;
    int sA = col[eA];
    float fA = exf1[eA];
    f16x4 hA = *(const f16x4*)(hb + (size_t)sA * 64);
    f32x4 vA = { (float)hA[0], (float)hA[1], (float)hA[2], (float)hA[3] };
    den += fA; acc += fA * vA;
    e += 4;
  }
  {
    int eA = e + slot;
    if (eA < e1){
      int sA = col[eA];
      float fA = exf1[eA];
      f16x4 hA = *(const f16x4*)(hb + (size_t)sA * 64);
      f32x4 vA = { (float)hA[0], (float)hA[1], (float)hA[2], (float)hA[3] };
      den += fA; acc += fA * vA;
    }
  }

  #pragma unroll
  for (int off = 16; off <= 32; off <<= 1){
    acc += shflx4(acc, off);
    den += __shfl_xor(den, off);
  }

  // self loop
  float es = __expf(lrelu02(asrc[d] + adst[d]));
  f16x4 hs = *(const f16x4*)(hH + (size_t)d * 64 + cpos);
  f32x4 vs = { (float)hs[0], (float)hs[1], (float)hs[2], (float)hs[3] };
  acc += es * vs;
  den += es;

  if (slot == 0){
    float inv = 1.f / (den + 1e-16f);
    float4 b4 = *(const float4*)&bias[cpos];
    float4 o = make_float4(acc[0] * inv + b4.x, acc[1] * inv + b4.y, acc[2] * inv + b4.z, acc[3] * inv + b4.w);
    *(float4*)(out + (size_t)d * 64 + cpos) = o;
  }
}

// ---------------- launch ----------------

extern "C" void kernel_launch(void* const* d_in, const int* in_sizes, int n_in,
                              void* d_out, int out_size, void* d_ws, size_t ws_size,
                              hipStream_t stream) {
  const float* x   = (const float*)d_in[0];
  const int*   ei  = (const int*)  d_in[1];
  const float* W0  = (const float*)d_in[2];
  const float* as0 = (const float*)d_in[3];
  const float* ad0 = (const float*)d_in[4];
  const float* b0  = (const float*)d_in[5];
  const float* W1  = (const float*)d_in[6];
  const float* as1 = (const float*)d_in[7];
  const float* ad1 = (const float*)d_in[8];
  const float* b1  = (const float*)d_in[9];
  const float* W2  = (const float*)d_in[10];
  const float* as2 = (const float*)d_in[11];
  const float* ad2 = (const float*)d_in[12];
  const float* b2  = (const float*)d_in[13];
  float* out = (float*)d_out;

  auto al = [](size_t v){ return (v + 255) & ~(size_t)255; };
  char* p = (char*)d_ws;
  int*      row_ptr = (int*)p;      p += al((NODES + 1) * sizeof(int));
  int*      cnt     = (int*)p;      p += al(NODES * sizeof(int));
  int*      bsums   = (int*)p;      p += al(64 * sizeof(int));
  int*      col     = (int*)p;      p += al(EDGES * sizeof(int));
  int*      dstarr  = (int*)p;      p += al(EDGES * sizeof(int));
  float*    exf     = (float*)p;    p += al((size_t)EDGES * 4 * sizeof(float));   // L0 exf[e][4]; L2 reuses as exf1[e]
  float*    asrc    = (float*)p;    p += al(NODES * 4 * sizeof(float));
  float*    adst    = (float*)p;    p += al(NODES * 4 * sizeof(float));
  _Float16* xh      = (_Float16*)p; p += al((size_t)NODES * 64 * sizeof(_Float16));
  _Float16* hH      = (_Float16*)p; p += al((size_t)NODES * 256 * sizeof(_Float16));
  _Float16* actb    = (_Float16*)p; p += al((size_t)NODES * 256 * sizeof(_Float16));
  _Float16* Wt0     = (_Float16*)p; p += al(256 * 64 * sizeof(_Float16));
  _Float16* Wt1     = (_Float16*)p; p += al(256 * 256 * sizeof(_Float16));
  _Float16* Wt2     = (_Float16*)p; p += al(64 * 256 * sizeof(_Float16));
  float*    ws0     = (float*)p;    p += al(256 * sizeof(float));
  float*    wd0     = (float*)p;    p += al(256 * sizeof(float));

  // ---- prep ----
  gat_cvt_h<<<(NODES * 64 / 4 + 255) / 256, 256, 0, stream>>>(x, xh, NODES * 64 / 4);
  gat_wt_all<<<576, 256, 0, stream>>>(W0, W1, W2, Wt0, Wt1, Wt2);
  gat_ws0<<<1, 256, 0, stream>>>(W0, as0, ad0, ws0, wd0);

  // ---- CSR build (by dst) ----
  gat_zero<<<(NODES + 255) / 256, 256, 0, stream>>>(cnt, NODES);
  gat_hist<<<(EDGES + 255) / 256, 256, 0, stream>>>(ei, cnt);
  gat_blocksum<<<NB_SCAN, 256, 0, stream>>>(cnt, bsums);
  gat_scan_bsums<<<1, 64, 0, stream>>>(bsums, NB_SCAN);
  gat_rowptr<<<NB_SCAN, 256, 0, stream>>>(cnt, bsums, row_ptr);
  gat_scatter<<<(EDGES + 255) / 256, 256, 0, stream>>>(ei, row_ptr, cnt, col, dstarr);

  const int nodeBlocks = (NODES + 3) / 4;
  const int gemmBlocks = (NODES + 63) / 64;
  const int edgeBlocks = (EDGES + 255) / 256;

  // ---- Layer 0 (swapped): attn in input space, edge exps, aggregate x, block-diag GEMM + bias + ELU ----
  gat_attn0<<<nodeBlocks, 256, 0, stream>>>(xh, ws0, wd0, asrc, adst, NODES);
  gat_edge_exp0<<<edgeBlocks, 256, 0, stream>>>(col, dstarr, asrc, adst, exf);
  gat_aggregate_in64<<<nodeBlocks, 256, 0, stream>>>(xh, exf, asrc, adst, row_ptr, col, hH);
  gat_gemm_bd<<<gemmBlocks, 256, 0, stream>>>(hH, Wt0, b0, actb, NODES);

  // ---- Layer 1: actb @ W1 -> hH; attn; fused-exp aggregate (round-5 structure, unroll 8) ----
  gat_gemm_mfma<256, 256><<<gemmBlocks, 256, 0, stream>>>(actb, Wt1, hH, NODES);
  gat_attn4<<<nodeBlocks, 256, 0, stream>>>(hH, as1, ad1, asrc, adst, NODES);
  gat_aggregate4<<<nodeBlocks, 256, 0, stream>>>(hH, asrc, adst, row_ptr, col, b1, actb);

  // ---- Layer 2: actb @ W2 -> hH (64ch); attn; edge exps; slot-based aggregate ----
  gat_gemm_mfma<256, 64><<<gemmBlocks, 256, 0, stream>>>(actb, Wt2, hH, NODES);
  gat_attn1<<<nodeBlocks, 256, 0, stream>>>(hH, as2, ad2, asrc, adst, NODES);
  gat_edge_exp1h<<<edgeBlocks, 256, 0, stream>>>(col, dstarr, asrc, adst, exf);
  gat_aggregate1n<<<nodeBlocks, 256, 0, stream>>>(hH, exf, asrc, adst, row_ptr, col, b2, out);
}

// Round 8
// 347.150 us; speedup vs baseline: 1.3792x; 1.0756x over previous
//
#include <hip/hip_runtime.h>
#include <hip/hip_fp16.h>
#include <math.h>

#define NODES 50000
#define EDGES 800000
#define NB_SCAN ((NODES + 1023) / 1024)

typedef __attribute__((ext_vector_type(8))) _Float16 f16x8;
typedef __attribute__((ext_vector_type(4))) _Float16 f16x4;
typedef __attribute__((ext_vector_type(4))) float f32x4;

__device__ __forceinline__ float lrelu02(float x){ return x > 0.f ? x : 0.2f * x; }

__device__ __forceinline__ f32x4 shflx4(f32x4 v, int m){
  f32x4 r;
  r[0] = __shfl_xor(v[0], m); r[1] = __shfl_xor(v[1], m);
  r[2] = __shfl_xor(v[2], m); r[3] = __shfl_xor(v[3], m);
  return r;
}

// ---------------- CSR build ----------------

__global__ __launch_bounds__(256) void gat_zero(int* __restrict__ p, int n){
  int i = blockIdx.x * 256 + threadIdx.x;
  if (i < n) p[i] = 0;
}

__global__ __launch_bounds__(256) void gat_hist(const int* __restrict__ ei, int* __restrict__ cnt){
  int e = blockIdx.x * 256 + threadIdx.x;
  if (e < EDGES) atomicAdd(&cnt[ei[EDGES + e]], 1);
}

__global__ __launch_bounds__(256) void gat_blocksum(const int* __restrict__ cnt, int* __restrict__ bsums){
  __shared__ int sd[256];
  int t = threadIdx.x, b = blockIdx.x;
  int base = b * 1024 + t * 4, s = 0;
  #pragma unroll
  for (int j = 0; j < 4; j++){ int i = base + j; if (i < NODES) s += cnt[i]; }
  sd[t] = s; __syncthreads();
  for (int o = 128; o > 0; o >>= 1){ if (t < o) sd[t] += sd[t + o]; __syncthreads(); }
  if (t == 0) bsums[b] = sd[0];
}

__global__ void gat_scan_bsums(int* bsums, int nb){
  if (threadIdx.x == 0 && blockIdx.x == 0){
    int run = 0;
    for (int i = 0; i < nb; i++){ int v = bsums[i]; bsums[i] = run; run += v; }
  }
}

__global__ __launch_bounds__(256) void gat_rowptr(int* __restrict__ cnt, const int* __restrict__ bsums,
                                                  int* __restrict__ row_ptr){
  __shared__ int sd[256];
  int t = threadIdx.x, b = blockIdx.x;
  int base = b * 1024 + t * 4;
  int c[4]; int s = 0;
  #pragma unroll
  for (int j = 0; j < 4; j++){
    int i = base + j;
    c[j] = (i < NODES) ? cnt[i] : 0;
    s += c[j];
    if (i < NODES) cnt[i] = 0;
  }
  sd[t] = s; __syncthreads();
  for (int o = 1; o < 256; o <<= 1){
    int v = (t >= o) ? sd[t - o] : 0;
    __syncthreads();
    if (t >= o) sd[t] += v;
    __syncthreads();
  }
  int off = bsums[b] + sd[t] - s;
  #pragma unroll
  for (int j = 0; j < 4; j++){
    int i = base + j;
    if (i < NODES){ row_ptr[i] = off; off += c[j]; }
  }
  if (b == 0 && t == 0) row_ptr[NODES] = EDGES;
}

__global__ __launch_bounds__(256) void gat_scatter(const int* __restrict__ ei, const int* __restrict__ row_ptr,
                                                    int* __restrict__ fill, int* __restrict__ col,
                                                    int* __restrict__ dstarr){
  int e = blockIdx.x * 256 + threadIdx.x;
  if (e < EDGES){
    int s = ei[e], d = ei[EDGES + e];
    int pos = row_ptr[d] + atomicAdd(&fill[d], 1);
    col[pos] = s;
    dstarr[pos] = d;
  }
}

// ---------------- fused prep: x->fp16, W transposes, projected attn vectors ----------------
// blocks 0..3124: cvt x (3125*256*4 = 3.2M floats); 3125..3700: Wt; 3701: ws0

__global__ __launch_bounds__(256) void gat_prep(const float* __restrict__ x, _Float16* __restrict__ xh,
                                                const float* __restrict__ W0, const float* __restrict__ W1,
                                                const float* __restrict__ W2,
                                                _Float16* __restrict__ Wt0, _Float16* __restrict__ Wt1,
                                                _Float16* __restrict__ Wt2,
                                                const float* __restrict__ as0, const float* __restrict__ ad0,
                                                float* __restrict__ ws, float* __restrict__ wd){
  int b = blockIdx.x;
  int t = threadIdx.x;
  if (b < 3125){
    int i = b * 256 + t;   // < 800000 float4s
    float4 v = *(const float4*)(x + (size_t)i * 4);
    f16x4 h = { (_Float16)v.x, (_Float16)v.y, (_Float16)v.z, (_Float16)v.w };
    *(f16x4*)(xh + (size_t)i * 4) = h;
  } else if (b < 3701){
    int k = b - 3125;      // 0..575
    if (k < 64){
      Wt0[(size_t)t * 64 + k] = (_Float16)W0[(size_t)k * 256 + t];
    } else if (k < 320){
      int kk = k - 64;
      Wt1[(size_t)t * 256 + kk] = (_Float16)W1[(size_t)kk * 256 + t];
    } else {
      int kk = k - 320;
      if (t < 64) Wt2[(size_t)t * 256 + kk] = (_Float16)W2[(size_t)kk * 64 + t];
    }
  } else {
    int h = t >> 6, c = t & 63;
    float s = 0.f, d = 0.f;
    for (int cc = 0; cc < 64; cc++){
      float w = W0[(size_t)c * 256 + h * 64 + cc];
      s += w * as0[h * 64 + cc];
      d += w * ad0[h * 64 + cc];
    }
    ws[h * 64 + c] = s;
    wd[h * 64 + c] = d;
  }
}

// ---------------- MFMA fp16 GEMM with fused attention-coefficient epilogue ----------------
// C[M,N] = A[M,K] @ W[K,N], Wt = W^T [N][K].
// ATTN=4: N=256, wave w == head w; writes asrc/adst[row*4+w].
// ATTN=1: N=64, cross-wave LDS reduce; writes asrc/adst[row].
// ATTN=0: plain GEMM.

template<int K, int N, int ATTN>
__global__ __launch_bounds__(256) void gat_gemm_mfma(const _Float16* __restrict__ A, const _Float16* __restrict__ Wt,
                                                      _Float16* __restrict__ C,
                                                      const float* __restrict__ a_srcv, const float* __restrict__ a_dstv,
                                                      float* __restrict__ asrc, float* __restrict__ adst, int M){
  constexpr int NT = N / 64;
  constexpr int LDT = 40;
  __shared__ _Float16 As[64][LDT];
  __shared__ _Float16 Bs[N][LDT];

  int tid = threadIdx.x;
  int w = tid >> 6, l = tid & 63;
  int lg = l >> 4, lr = l & 15;
  int bm = blockIdx.x * 64;

  f32x4 acc[4][NT];
  #pragma unroll
  for (int m = 0; m < 4; m++)
    #pragma unroll
    for (int n = 0; n < NT; n++)
      acc[m][n] = (f32x4){0.f, 0.f, 0.f, 0.f};

  int ar = tid >> 2;
  int akc = (tid & 3) * 8;
  bool avalid = (bm + ar) < M;
  const _Float16* aptr = A + (size_t)(bm + ar) * K + akc;

  for (int k0 = 0; k0 < K; k0 += 32){
    float4 av = avalid ? *(const float4*)(aptr + k0) : make_float4(0.f, 0.f, 0.f, 0.f);
    __syncthreads();
    *(float4*)&As[ar][akc] = av;
    #pragma unroll
    for (int c = 0; c < N / 64; c++){
      int idx = c * 256 + tid;
      int n = idx >> 2, kc = (idx & 3) * 8;
      *(float4*)&Bs[n][kc] = *(const float4*)(Wt + (size_t)n * K + k0 + kc);
    }
    __syncthreads();

    f16x8 af[4], bf[NT];
    #pragma unroll
    for (int m = 0; m < 4; m++) af[m] = *(const f16x8*)&As[16 * m + lr][8 * lg];
    #pragma unroll
    for (int n = 0; n < NT; n++) bf[n] = *(const f16x8*)&Bs[w * (N / 4) + 16 * n + lr][8 * lg];
    #pragma unroll
    for (int m = 0; m < 4; m++)
      #pragma unroll
      for (int n = 0; n < NT; n++)
        acc[m][n] = __builtin_amdgcn_mfma_f32_16x16x32_f16(af[m], bf[n], acc[m][n], 0, 0, 0);
  }

  #pragma unroll
  for (int m = 0; m < 4; m++){
    #pragma unroll
    for (int j = 0; j < 4; j++){
      int row = bm + 16 * m + 4 * lg + j;
      if (row < M){
        #pragma unroll
        for (int n = 0; n < NT; n++)
          C[(size_t)row * N + w * (N / 4) + 16 * n + lr] = (_Float16)acc[m][n][j];
      }
    }
  }

  if constexpr (ATTN == 4){
    // wave w == head w; cols of head w are exactly w*64 + 16n + lr
    float avs[4], avd[4];
    #pragma unroll
    for (int n = 0; n < 4; n++){
      avs[n] = a_srcv[w * 64 + 16 * n + lr];
      avd[n] = a_dstv[w * 64 + 16 * n + lr];
    }
    #pragma unroll
    for (int m = 0; m < 4; m++){
      #pragma unroll
      for (int j = 0; j < 4; j++){
        float s1 = acc[m][0][j] * avs[0] + acc[m][1][j] * avs[1] + acc[m][2][j] * avs[2] + acc[m][3][j] * avs[3];
        float s2 = acc[m][0][j] * avd[0] + acc[m][1][j] * avd[1] + acc[m][2][j] * avd[2] + acc[m][3][j] * avd[3];
        #pragma unroll
        for (int o = 8; o > 0; o >>= 1){ s1 += __shfl_xor(s1, o); s2 += __shfl_xor(s2, o); }
        int row = bm + 16 * m + 4 * lg + j;
        if (lr == 0 && row < M){
          asrc[row * 4 + w] = s1;
          adst[row * 4 + w] = s2;
        }
      }
    }
  }
  if constexpr (ATTN == 1){
    __shared__ float sred[2][4][64];
    float av = a_srcv[w * 16 + lr], dv = a_dstv[w * 16 + lr];
    #pragma unroll
    for (int m = 0; m < 4; m++){
      #pragma unroll
      for (int j = 0; j < 4; j++){
        float s1 = acc[m][0][j] * av;
        float s2 = acc[m][0][j] * dv;
        #pragma unroll
        for (int o = 8; o > 0; o >>= 1){ s1 += __shfl_xor(s1, o); s2 += __shfl_xor(s2, o); }
        if (lr == 0){
          sred[0][w][16 * m + 4 * lg + j] = s1;
          sred[1][w][16 * m + 4 * lg + j] = s2;
        }
      }
    }
    __syncthreads();
    if (tid < 64){
      int row = bm + tid;
      if (row < M){
        asrc[row] = sred[0][0][tid] + sred[0][1][tid] + sred[0][2][tid] + sred[0][3][tid];
        adst[row] = sred[1][0][tid] + sred[1][1][tid] + sred[1][2][tid] + sred[1][3][tid];
      }
    }
  }
}

// ---------------- block-diagonal per-head GEMM (layer 0 post-aggregate), no LDS ----------------

__global__ __launch_bounds__(256) void gat_gemm_bd(const _Float16* __restrict__ A, const _Float16* __restrict__ Bt,
                                                    const float* __restrict__ bias, _Float16* __restrict__ C, int M){
  int tid = threadIdx.x;
  int w = tid >> 6, l = tid & 63;
  int lg = l >> 4, lr = l & 15;
  int bm = blockIdx.x * 64;

  f32x4 acc[4][4];
  #pragma unroll
  for (int m = 0; m < 4; m++)
    #pragma unroll
    for (int n = 0; n < 4; n++)
      acc[m][n] = (f32x4){0.f, 0.f, 0.f, 0.f};

  f16x8 zf = {};
  #pragma unroll
  for (int ks = 0; ks < 2; ks++){
    int koff = ks * 32;
    f16x8 af[4], bf[4];
    #pragma unroll
    for (int m = 0; m < 4; m++){
      int row = bm + 16 * m + lr;
      af[m] = (row < M) ? *(const f16x8*)(A + (size_t)row * 256 + w * 64 + koff + 8 * lg) : zf;
    }
    #pragma unroll
    for (int n = 0; n < 4; n++)
      bf[n] = *(const f16x8*)(Bt + (size_t)(w * 64 + 16 * n + lr) * 64 + koff + 8 * lg);
    #pragma unroll
    for (int m = 0; m < 4; m++)
      #pragma unroll
      for (int n = 0; n < 4; n++)
        acc[m][n] = __builtin_amdgcn_mfma_f32_16x16x32_f16(af[m], bf[n], acc[m][n], 0, 0, 0);
  }

  #pragma unroll
  for (int m = 0; m < 4; m++){
    #pragma unroll
    for (int j = 0; j < 4; j++){
      int row = bm + 16 * m + 4 * lg + j;
      if (row < M){
        #pragma unroll
        for (int n = 0; n < 4; n++){
          int cc = w * 64 + 16 * n + lr;
          float o = acc[m][n][j] + bias[cc];
          o = o > 0.f ? o : expm1f(o);
          C[(size_t)row * 256 + cc] = (_Float16)o;
        }
      }
    }
  }
}

// ---------------- layer-0 attention (from x via projected vectors) ----------------

__global__ __launch_bounds__(256) void gat_attn0(const _Float16* __restrict__ xh, const float* __restrict__ ws,
                                                  const float* __restrict__ wd,
                                                  float* __restrict__ asrc, float* __restrict__ adst, int N){
  int lane = threadIdx.x & 63;
  int wid = threadIdx.x >> 6;
  int n = blockIdx.x * 4 + wid;
  if (n >= N) return;
  float v = (float)xh[(size_t)n * 64 + lane];
  #pragma unroll
  for (int h = 0; h < 4; h++){
    float s1 = v * ws[h * 64 + lane];
    float s2 = v * wd[h * 64 + lane];
    #pragma unroll
    for (int o = 32; o > 0; o >>= 1){ s1 += __shfl_xor(s1, o); s2 += __shfl_xor(s2, o); }
    if (lane == 0){ asrc[n * 4 + h] = s1; adst[n * 4 + h] = s2; }
  }
}

// ---------------- layer-0 edge exp precompute (CSR order) ----------------

__global__ __launch_bounds__(256) void gat_edge_exp0(const int* __restrict__ col, const int* __restrict__ dstarr,
                                                      const float* __restrict__ asrc, const float* __restrict__ adst,
                                                      float* __restrict__ exf){
  int i = blockIdx.x * 256 + threadIdx.x;
  if (i >= EDGES) return;
  int s = col[i], d = dstarr[i];
  float4 a = *(const float4*)&asrc[s * 4];
  float4 b = *(const float4*)&adst[d * 4];
  float4 r;
  r.x = __expf(lrelu02(a.x + b.x));
  r.y = __expf(lrelu02(a.y + b.y));
  r.z = __expf(lrelu02(a.z + b.z));
  r.w = __expf(lrelu02(a.w + b.w));
  *(float4*)&exf[(size_t)i * 4] = r;
}

// ---------------- layer-0 aggregate in 64-dim input space ----------------
// wave = 4 edge-slots x 16 lanes; lane loads f16x4 (8B) of one edge's row; shfl-reduce over slots.

__global__ __launch_bounds__(256) void gat_aggregate_in64(const _Float16* __restrict__ xh, const float* __restrict__ exf,
                                                           const float* __restrict__ asrc, const float* __restrict__ adst,
                                                           const int* __restrict__ row_ptr, const int* __restrict__ col,
                                                           _Float16* __restrict__ agg){
  int lane = threadIdx.x & 63;
  int wid = threadIdx.x >> 6;
  int d = blockIdx.x * 4 + wid;
  if (d >= NODES) return;
  int slot = lane >> 4;
  int cpos = (lane & 15) * 4;

  f32x4 acc0 = {0,0,0,0}, acc1 = {0,0,0,0}, acc2 = {0,0,0,0}, acc3 = {0,0,0,0};
  f32x4 den = {0,0,0,0};

  int e0 = row_ptr[d], e1 = row_ptr[d + 1];
  const _Float16* xb = xh + cpos;
  int e = e0;
  for (; e + 8 <= e1; e += 8){
    int eA = e + slot, eB = e + 4 + slot;
    int sA = col[eA], sB = col[eB];
    float4 fA = *(const float4*)(exf + (size_t)eA * 4);
    float4 fB = *(const float4*)(exf + (size_t)eB * 4);
    f16x4 hA = *(const f16x4*)(xb + (size_t)sA * 64);
    f16x4 hB = *(const f16x4*)(xb + (size_t)sB * 64);
    f32x4 vA = { (float)hA[0], (float)hA[1], (float)hA[2], (float)hA[3] };
    f32x4 vB = { (float)hB[0], (float)hB[1], (float)hB[2], (float)hB[3] };
    den += (f32x4){ fA.x + fB.x, fA.y + fB.y, fA.z + fB.z, fA.w + fB.w };
    acc0 += fA.x * vA + fB.x * vB;
    acc1 += fA.y * vA + fB.y * vB;
    acc2 += fA.z * vA + fB.z * vB;
    acc3 += fA.w * vA + fB.w * vB;
  }
  if (e + 4 <= e1){
    int eA = e + slot;
    int sA = col[eA];
    float4 fA = *(const float4*)(exf + (size_t)eA * 4);
    f16x4 hA = *(const f16x4*)(xb + (size_t)sA * 64);
    f32x4 vA = { (float)hA[0], (float)hA[1], (float)hA[2], (float)hA[3] };
    den += (f32x4){ fA.x, fA.y, fA.z, fA.w };
    acc0 += fA.x * vA; acc1 += fA.y * vA; acc2 += fA.z * vA; acc3 += fA.w * vA;
    e += 4;
  }
  {
    int eA = e + slot;
    if (eA < e1){
      int sA = col[eA];
      float4 fA = *(const float4*)(exf + (size_t)eA * 4);
      f16x4 hA = *(const f16x4*)(xb + (size_t)sA * 64);
      f32x4 vA = { (float)hA[0], (float)hA[1], (float)hA[2], (float)hA[3] };
      den += (f32x4){ fA.x, fA.y, fA.z, fA.w };
      acc0 += fA.x * vA; acc1 += fA.y * vA; acc2 += fA.z * vA; acc3 += fA.w * vA;
    }
  }

  #pragma unroll
  for (int off = 16; off <= 32; off <<= 1){
    acc0 += shflx4(acc0, off);
    acc1 += shflx4(acc1, off);
    acc2 += shflx4(acc2, off);
    acc3 += shflx4(acc3, off);
    den  += shflx4(den,  off);
  }

  // self loop
  float4 a4 = *(const float4*)&asrc[d * 4];
  float4 b4 = *(const float4*)&adst[d * 4];
  float es0 = __expf(lrelu02(a4.x + b4.x));
  float es1 = __expf(lrelu02(a4.y + b4.y));
  float es2 = __expf(lrelu02(a4.z + b4.z));
  float es3 = __expf(lrelu02(a4.w + b4.w));
  f16x4 hs = *(const f16x4*)(xh + (size_t)d * 64 + cpos);
  f32x4 vs = { (float)hs[0], (float)hs[1], (float)hs[2], (float)hs[3] };
  acc0 += es0 * vs; acc1 += es1 * vs; acc2 += es2 * vs; acc3 += es3 * vs;
  den += (f32x4){ es0, es1, es2, es3 };

  if (slot == 0){
    float i0 = 1.f / (den[0] + 1e-16f), i1 = 1.f / (den[1] + 1e-16f);
    float i2 = 1.f / (den[2] + 1e-16f), i3 = 1.f / (den[3] + 1e-16f);
    _Float16* ob = agg + (size_t)d * 256 + cpos;
    f16x4 o0 = { (_Float16)(acc0[0]*i0), (_Float16)(acc0[1]*i0), (_Float16)(acc0[2]*i0), (_Float16)(acc0[3]*i0) };
    f16x4 o1 = { (_Float16)(acc1[0]*i1), (_Float16)(acc1[1]*i1), (_Float16)(acc1[2]*i1), (_Float16)(acc1[3]*i1) };
    f16x4 o2 = { (_Float16)(acc2[0]*i2), (_Float16)(acc2[1]*i2), (_Float16)(acc2[2]*i2), (_Float16)(acc2[3]*i2) };
    f16x4 o3 = { (_Float16)(acc3[0]*i3), (_Float16)(acc3[1]*i3), (_Float16)(acc3[2]*i3), (_Float16)(acc3[3]*i3) };
    *(f16x4*)(ob)       = o0;
    *(f16x4*)(ob + 64)  = o1;
    *(f16x4*)(ob + 128) = o2;
    *(f16x4*)(ob + 192) = o3;
  }
}

// ---------------- layer-1 aggregate (4 heads, 256ch), fused exp, unroll 4 (round-5 form) ----------------

__global__ __launch_bounds__(256) void gat_aggregate4(const _Float16* __restrict__ hH, const float* __restrict__ asrc,
                                                       const float* __restrict__ adst,
                                                       const int* __restrict__ row_ptr, const int* __restrict__ col,
                                                       const float* __restrict__ bias, _Float16* __restrict__ out){
  int lane = threadIdx.x & 63;
  int wid = threadIdx.x >> 6;
  int d = blockIdx.x * 4 + wid;
  if (d >= NODES) return;
  int q = lane >> 4;
  int co = lane * 4;

  float adq = adst[d * 4 + q];

  float ex = __expf(lrelu02(asrc[d * 4 + q] + adq));
  f16x4 hv = *(const f16x4*)(hH + (size_t)d * 256 + co);
  float4 acc = make_float4(ex * (float)hv[0], ex * (float)hv[1], ex * (float)hv[2], ex * (float)hv[3]);
  float den = ex;

  int e0 = row_ptr[d], e1 = row_ptr[d + 1];
  const _Float16* hbase = hH + co;
  int e = e0;
  for (; e + 4 <= e1; e += 4){
    int s0 = col[e], s1 = col[e + 1], s2 = col[e + 2], s3 = col[e + 3];
    float a0 = asrc[s0 * 4 + q], a1 = asrc[s1 * 4 + q], a2 = asrc[s2 * 4 + q], a3 = asrc[s3 * 4 + q];
    f16x4 h0 = *(const f16x4*)(hbase + (size_t)s0 * 256);
    f16x4 h1 = *(const f16x4*)(hbase + (size_t)s1 * 256);
    f16x4 h2 = *(const f16x4*)(hbase + (size_t)s2 * 256);
    f16x4 h3 = *(const f16x4*)(hbase + (size_t)s3 * 256);
    float x0 = __expf(lrelu02(a0 + adq));
    float x1 = __expf(lrelu02(a1 + adq));
    float x2 = __expf(lrelu02(a2 + adq));
    float x3 = __expf(lrelu02(a3 + adq));
    den += x0 + x1 + x2 + x3;
    acc.x += x0 * (float)h0[0] + x1 * (float)h1[0] + x2 * (float)h2[0] + x3 * (float)h3[0];
    acc.y += x0 * (float)h0[1] + x1 * (float)h1[1] + x2 * (float)h2[1] + x3 * (float)h3[1];
    acc.z += x0 * (float)h0[2] + x1 * (float)h1[2] + x2 * (float)h2[2] + x3 * (float)h3[2];
    acc.w += x0 * (float)h0[3] + x1 * (float)h1[3] + x2 * (float)h2[3] + x3 * (float)h3[3];
  }
  for (; e < e1; e++){
    int s0 = col[e];
    float a0 = asrc[s0 * 4 + q];
    f16x4 h0 = *(const f16x4*)(hbase + (size_t)s0 * 256);
    float x0 = __expf(lrelu02(a0 + adq));
    den += x0;
    acc.x += x0 * (float)h0[0]; acc.y += x0 * (float)h0[1];
    acc.z += x0 * (float)h0[2]; acc.w += x0 * (float)h0[3];
  }

  float inv = 1.f / (den + 1e-16f);
  float4 b4 = *(const float4*)&bias[co];
  float4 o = make_float4(acc.x * inv + b4.x, acc.y * inv + b4.y, acc.z * inv + b4.z, acc.w * inv + b4.w);
  o.x = o.x > 0.f ? o.x : expm1f(o.x);
  o.y = o.y > 0.f ? o.y : expm1f(o.y);
  o.z = o.z > 0.f ? o.z : expm1f(o.z);
  o.w = o.w > 0.f ? o.w : expm1f(o.w);
  f16x4 oh = { (_Float16)o.x, (_Float16)o.y, (_Float16)o.z, (_Float16)o.w };
  *(f16x4*)(out + (size_t)d * 256 + co) = oh;
}

// ---------------- layer-2 aggregate (1 head, 64ch): 4 edge-slots x 16 lanes, inline exp ----------------

__global__ __launch_bounds__(256) void gat_aggregate1n(const _Float16* __restrict__ hH,
                                                        const float* __restrict__ asrc, const float* __restrict__ adst,
                                                        const int* __restrict__ row_ptr, const int* __restrict__ col,
                                                        const float* __restrict__ bias, float* __restrict__ out){
  int lane = threadIdx.x & 63;
  int wid = threadIdx.x >> 6;
  int d = blockIdx.x * 4 + wid;
  if (d >= NODES) return;
  int slot = lane >> 4;
  int cpos = (lane & 15) * 4;

  float adq = adst[d];
  f32x4 acc = {0,0,0,0};
  float den = 0.f;

  int e0 = row_ptr[d], e1 = row_ptr[d + 1];
  const _Float16* hb = hH + cpos;
  int e = e0;
  for (; e + 8 <= e1; e += 8){
    int eA = e + slot, eB = e + 4 + slot;
    int sA = col[eA], sB = col[eB];
    float fA = __expf(lrelu02(asrc[sA] + adq));
    float fB = __expf(lrelu02(asrc[sB] + adq));
    f16x4 hA = *(const f16x4*)(hb + (size_t)sA * 64);
    f16x4 hB = *(const f16x4*)(hb + (size_t)sB * 64);
    f32x4 vA = { (float)hA[0], (float)hA[1], (float)hA[2], (float)hA[3] };
    f32x4 vB = { (float)hB[0], (float)hB[1], (float)hB[2], (float)hB[3] };
    den += fA + fB;
    acc += fA * vA + fB * vB;
  }
  if (e + 4 <= e1){
    int eA = e + slot;
    int sA = col[eA];
    float fA = __expf(lrelu02(asrc[sA] + adq));
    f16x4 hA = *(const f16x4*)(hb + (size_t)sA * 64);
    f32x4 vA = { (float)hA[0], (float)hA[1], (float)hA[2], (float)hA[3] };
    den += fA; acc += fA * vA;
    e += 4;
  }
  {
    int eA = e + slot;
    if (eA < e1){
      int sA = col[eA];
      float fA = __expf(lrelu02(asrc[sA] + adq));
      f16x4 hA = *(const f16x4*)(hb + (size_t)sA * 64);
      f32x4 vA = { (float)hA[0], (float)hA[1], (float)hA[2], (float)hA[3] };
      den += fA; acc += fA * vA;
    }
  }

  #pragma unroll
  for (int off = 16; off <= 32; off <<= 1){
    acc += shflx4(acc, off);
    den += __shfl_xor(den, off);
  }

  // self loop
  float es = __expf(lrelu02(asrc[d] + adq));
  f16x4 hs = *(const f16x4*)(hH + (size_t)d * 64 + cpos);
  f32x4 vs = { (float)hs[0], (float)hs[1], (float)hs[2], (float)hs[3] };
  acc += es * vs;
  den += es;

  if (slot == 0){
    float inv = 1.f / (den + 1e-16f);
    float4 b4 = *(const float4*)&bias[cpos];
    float4 o = make_float4(acc[0] * inv + b4.x, acc[1] * inv + b4.y, acc[2] * inv + b4.z, acc[3] * inv + b4.w);
    *(float4*)(out + (size_t)d * 64 + cpos) = o;
  }
}

// ---------------- launch ----------------

extern "C" void kernel_launch(void* const* d_in, const int* in_sizes, int n_in,
                              void* d_out, int out_size, void* d_ws, size_t ws_size,
                              hipStream_t stream) {
  const float* x   = (const float*)d_in[0];
  const int*   ei  = (const int*)  d_in[1];
  const float* W0  = (const float*)d_in[2];
  const float* as0 = (const float*)d_in[3];
  const float* ad0 = (const float*)d_in[4];
  const float* b0  = (const float*)d_in[5];
  const float* W1  = (const float*)d_in[6];
  const float* as1 = (const float*)d_in[7];
  const float* ad1 = (const float*)d_in[8];
  const float* b1  = (const float*)d_in[9];
  const float* W2  = (const float*)d_in[10];
  const float* as2 = (const float*)d_in[11];
  const float* ad2 = (const float*)d_in[12];
  const float* b2  = (const float*)d_in[13];
  float* out = (float*)d_out;

  auto al = [](size_t v){ return (v + 255) & ~(size_t)255; };
  char* p = (char*)d_ws;
  int*      row_ptr = (int*)p;      p += al((NODES + 1) * sizeof(int));
  int*      cnt     = (int*)p;      p += al(NODES * sizeof(int));
  int*      bsums   = (int*)p;      p += al(64 * sizeof(int));
  int*      col     = (int*)p;      p += al(EDGES * sizeof(int));
  int*      dstarr  = (int*)p;      p += al(EDGES * sizeof(int));
  float*    exf     = (float*)p;    p += al((size_t)EDGES * 4 * sizeof(float));
  float*    asrc    = (float*)p;    p += al(NODES * 4 * sizeof(float));
  float*    adst    = (float*)p;    p += al(NODES * 4 * sizeof(float));
  _Float16* xh      = (_Float16*)p; p += al((size_t)NODES * 64 * sizeof(_Float16));
  _Float16* hH      = (_Float16*)p; p += al((size_t)NODES * 256 * sizeof(_Float16));
  _Float16* actb    = (_Float16*)p; p += al((size_t)NODES * 256 * sizeof(_Float16));
  _Float16* Wt0     = (_Float16*)p; p += al(256 * 64 * sizeof(_Float16));
  _Float16* Wt1     = (_Float16*)p; p += al(256 * 256 * sizeof(_Float16));
  _Float16* Wt2     = (_Float16*)p; p += al(64 * 256 * sizeof(_Float16));
  float*    ws0     = (float*)p;    p += al(256 * sizeof(float));
  float*    wd0     = (float*)p;    p += al(256 * sizeof(float));

  // ---- fused prep ----
  gat_prep<<<3702, 256, 0, stream>>>(x, xh, W0, W1, W2, Wt0, Wt1, Wt2, as0, ad0, ws0, wd0);

  // ---- CSR build (by dst) ----
  gat_zero<<<(NODES + 255) / 256, 256, 0, stream>>>(cnt, NODES);
  gat_hist<<<(EDGES + 255) / 256, 256, 0, stream>>>(ei, cnt);
  gat_blocksum<<<NB_SCAN, 256, 0, stream>>>(cnt, bsums);
  gat_scan_bsums<<<1, 64, 0, stream>>>(bsums, NB_SCAN);
  gat_rowptr<<<NB_SCAN, 256, 0, stream>>>(cnt, bsums, row_ptr);
  gat_scatter<<<(EDGES + 255) / 256, 256, 0, stream>>>(ei, row_ptr, cnt, col, dstarr);

  const int nodeBlocks = (NODES + 3) / 4;
  const int gemmBlocks = (NODES + 63) / 64;
  const int edgeBlocks = (EDGES + 255) / 256;

  // ---- Layer 0 (swapped): attn in input space, edge exps, aggregate x, block-diag GEMM + bias + ELU ----
  gat_attn0<<<nodeBlocks, 256, 0, stream>>>(xh, ws0, wd0, asrc, adst, NODES);
  gat_edge_exp0<<<edgeBlocks, 256, 0, stream>>>(col, dstarr, asrc, adst, exf);
  gat_aggregate_in64<<<nodeBlocks, 256, 0, stream>>>(xh, exf, asrc, adst, row_ptr, col, hH);
  gat_gemm_bd<<<gemmBlocks, 256, 0, stream>>>(hH, Wt0, b0, actb, NODES);

  // ---- Layer 1: actb @ W1 -> hH (+ fused attn); aggregate ----
  gat_gemm_mfma<256, 256, 4><<<gemmBlocks, 256, 0, stream>>>(actb, Wt1, hH, as1, ad1, asrc, adst, NODES);
  gat_aggregate4<<<nodeBlocks, 256, 0, stream>>>(hH, asrc, adst, row_ptr, col, b1, actb);

  // ---- Layer 2: actb @ W2 -> hH (64ch, + fused attn); aggregate with inline exp ----
  gat_gemm_mfma<256, 64, 1><<<gemmBlocks, 256, 0, stream>>>(actb, Wt2, hH, as2, ad2, asrc, adst, NODES);
  gat_aggregate1n<<<nodeBlocks, 256, 0, stream>>>(hH, asrc, adst, row_ptr, col, b2, out);
}